// Round 5
// baseline (246.353 us; speedup 1.0000x reference)
//
#include <hip/hip_runtime.h>
#include <hip/hip_bf16.h>
#include <math.h>

#define D 64
#define K_CODES 8192
#define M_QUERIES 32768
#define SLICES 4
#define CODES_PER_SLICE (K_CODES / SLICES)  // 2048
#define CHUNK 64
#define NCHUNK (CODES_PER_SLICE / CHUNK)    // 32
#define QPB 128                              // queries per block = 4 waves * 32
#define TAU_V 4e-3f                          // gap threshold in v units (d2 gap = 2*v gap)

typedef __attribute__((ext_vector_type(8))) short bf16x8;
typedef __attribute__((ext_vector_type(4))) float f32x4;

__device__ __forceinline__ unsigned short f2bf(float x) {
    __hip_bfloat16 h = __float2bfloat16(x);
    return *reinterpret_cast<unsigned short*>(&h);
}
__device__ __forceinline__ float bf2f(unsigned short s) {
    __hip_bfloat16 h;
    *reinterpret_cast<unsigned short*>(&h) = s;
    return __bfloat162float(h);
}

// ---- K0: split emb into bf16 hi/lo, he' = 0.5*||e||^2 + 128, zero counter ----
__global__ __launch_bounds__(256) void k0_split(const float* __restrict__ emb,
                                                unsigned short* __restrict__ e_hi,
                                                unsigned short* __restrict__ e_lo,
                                                float* __restrict__ halfee,
                                                int* __restrict__ ws_cnt) {
    const int wid = threadIdx.x >> 6, l = threadIdx.x & 63;
    const int c = blockIdx.x * 4 + wid;
    if (c == 0 && l == 0) *ws_cnt = 0;
    float e = emb[(size_t)c * D + l];
    unsigned short h = f2bf(e);
    float r = e - bf2f(h);
    e_hi[(size_t)c * D + l] = h;
    e_lo[(size_t)c * D + l] = f2bf(r);
    float s = e * e;
#pragma unroll
    for (int m = 1; m < 64; m <<= 1) s += __shfl_xor(s, m);
    if (l == 0) halfee[c] = 0.5f * s + 128.0f;
}

// ---- K1: MFMA scoring v = he' - z.e (bf16 split), packed top-2 argmin ----
// NO min-waves hint: (256,4) forced 64 VGPR (283MB spill), (256,2) forced 76
// (45MB spill). Natural allocation is ~112 VGPR = no spill, and 112<=128
// already allows 16 waves/CU with our 33KB LDS (4 blocks/CU).
__global__ __launch_bounds__(256) void k1_mfma(const float* __restrict__ z,
                                               const unsigned short* __restrict__ e_hi,
                                               const unsigned short* __restrict__ e_lo,
                                               const float* __restrict__ halfee,
                                               float4* __restrict__ ws_part) {
    __shared__ unsigned short ldshi[2][CHUNK * 64];
    __shared__ unsigned short ldslo[2][CHUNK * 64];
    __shared__ float ldshe[2][CHUNK];

    const int tid = threadIdx.x;
    const int wid = tid >> 6;
    const int l   = tid & 63;
    const int l15 = l & 15, l16 = l >> 4;
    const int slice = blockIdx.y;
    const int cslice0 = slice * CODES_PER_SLICE;

    // this wave's 32 queries -> negated bf16 hi/lo B-fragments in regs
    const int qw0 = blockIdx.x * QPB + wid * 32;
    bf16x8 qh[2][2], ql[2][2];
#pragma unroll
    for (int qt = 0; qt < 2; ++qt)
#pragma unroll
        for (int kk = 0; kk < 2; ++kk) {
            const float* src = z + (size_t)(qw0 + qt * 16 + l15) * D + kk * 32 + l16 * 8;
            float4 f0 = *(const float4*)(src);
            float4 f1 = *(const float4*)(src + 4);
            float f[8] = {f0.x, f0.y, f0.z, f0.w, f1.x, f1.y, f1.z, f1.w};
            bf16x8 h, lo;
#pragma unroll
            for (int j = 0; j < 8; ++j) {
                float x = -f[j];
                unsigned short hh = f2bf(x);
                float r = x - bf2f(hh);
                h[j]  = (short)hh;
                lo[j] = (short)f2bf(r);
            }
            qh[qt][kk] = h;
            ql[qt][kk] = lo;
        }

    float g1[2] = {1e30f, 1e30f}, g2[2] = {1e30f, 1e30f};
    int   gi[2] = {0x7fffffff, 0x7fffffff};
    float4 rh[2], rl[2], rhe;

#define ISSUE_LOADS(c1)                                                          \
    {                                                                            \
        const char* bhi = (const char*)e_hi + (size_t)(cslice0 + (c1) * CHUNK) * 128; \
        const char* blo = (const char*)e_lo + (size_t)(cslice0 + (c1) * CHUNK) * 128; \
        _Pragma("unroll") for (int p = 0; p < 2; ++p) {                          \
            int idx = p * 256 + tid;                                             \
            rh[p] = *(const float4*)(bhi + idx * 16);                            \
            rl[p] = *(const float4*)(blo + idx * 16);                            \
        }                                                                        \
        if (tid < 16)                                                            \
            rhe = *(const float4*)((const char*)halfee +                         \
                                   (size_t)(cslice0 + (c1) * CHUNK) * 4 + tid * 16); \
    }

#define WRITE_LDS(buf)                                                           \
    {                                                                            \
        _Pragma("unroll") for (int p = 0; p < 2; ++p) {                          \
            int idx = p * 256 + tid;                                             \
            int r = idx >> 3, cc = idx & 7;                                      \
            int off = r * 128 + (cc ^ (r & 7)) * 16;                             \
            *(float4*)((char*)ldshi[buf] + off) = rh[p];                         \
            *(float4*)((char*)ldslo[buf] + off) = rl[p];                         \
        }                                                                        \
        if (tid < 16) *(float4*)((char*)ldshe[buf] + tid * 16) = rhe;            \
    }

#define COMPUTE(bufc, cbase)                                                     \
    {                                                                            \
        const char* bh  = (const char*)ldshi[bufc];                              \
        const char* bl  = (const char*)ldslo[bufc];                              \
        const float* bhe = ldshe[bufc];                                          \
        float m1p[2] = {1e30f, 1e30f}, m2p[2] = {1e30f, 1e30f};                  \
        _Pragma("unroll") for (int ct = 0; ct < 4; ++ct) {                       \
            int R0 = ct * 16 + l15;                                              \
            int rowb = R0 * 128;                                                 \
            int sw0 = ((l16)     ^ (R0 & 7)) * 16;                               \
            int sw1 = ((4 + l16) ^ (R0 & 7)) * 16;                               \
            bf16x8 ah0 = *(const bf16x8*)(bh + rowb + sw0);                      \
            bf16x8 ah1 = *(const bf16x8*)(bh + rowb + sw1);                      \
            bf16x8 al0 = *(const bf16x8*)(bl + rowb + sw0);                      \
            bf16x8 al1 = *(const bf16x8*)(bl + rowb + sw1);                      \
            f32x4 he = *(const f32x4*)(bhe + ct * 16 + l16 * 4);                 \
            _Pragma("unroll") for (int qt = 0; qt < 2; ++qt) {                   \
                f32x4 va;                                                        \
                va = __builtin_amdgcn_mfma_f32_16x16x32_bf16(ah0, qh[qt][0], he, 0, 0, 0); \
                va = __builtin_amdgcn_mfma_f32_16x16x32_bf16(ah1, qh[qt][1], va, 0, 0, 0); \
                va = __builtin_amdgcn_mfma_f32_16x16x32_bf16(ah0, ql[qt][0], va, 0, 0, 0); \
                va = __builtin_amdgcn_mfma_f32_16x16x32_bf16(ah1, ql[qt][1], va, 0, 0, 0); \
                va = __builtin_amdgcn_mfma_f32_16x16x32_bf16(al0, qh[qt][0], va, 0, 0, 0); \
                va = __builtin_amdgcn_mfma_f32_16x16x32_bf16(al1, qh[qt][1], va, 0, 0, 0); \
                _Pragma("unroll") for (int j = 0; j < 4; ++j) {                  \
                    int pos = ct * 4 + j;                                        \
                    float vp = __int_as_float((__float_as_int(va[j]) & 0xFFFFFFF0) | pos); \
                    m2p[qt] = __builtin_amdgcn_fmed3f(vp, m1p[qt], m2p[qt]);     \
                    m1p[qt] = fminf(m1p[qt], vp);                                \
                }                                                                \
            }                                                                    \
        }                                                                        \
        _Pragma("unroll") for (int qt = 0; qt < 2; ++qt) {                       \
            float v1 = m1p[qt];                                                  \
            int   p1 = __float_as_int(v1) & 15;                                  \
            int code = (cbase) + l16 * 4 + ((p1 >> 2) << 4) + (p1 & 3);          \
            bool lt = v1 < g1[qt];                                               \
            g2[qt] = fminf(lt ? g1[qt] : g2[qt], lt ? m2p[qt] : v1);             \
            g1[qt] = lt ? v1 : g1[qt];                                           \
            gi[qt] = lt ? code : gi[qt];                                         \
        }                                                                        \
    }

    ISSUE_LOADS(0);
    WRITE_LDS(0);
    __syncthreads();
    for (int c = 0; c < NCHUNK; ++c) {
        const int cur = c & 1;
        if (c + 1 < NCHUNK) ISSUE_LOADS(c + 1);
        COMPUTE(cur, cslice0 + c * CHUNK);
        __syncthreads();
        if (c + 1 < NCHUNK) WRITE_LDS(cur ^ 1);
        __syncthreads();
    }

    // lanes {l15, l15+16, l15+32, l15+48} share a query, hold disjoint codes
#pragma unroll
    for (int qt = 0; qt < 2; ++qt) {
        float a1 = g1[qt], a2 = g2[qt];
        int   ai = gi[qt];
#pragma unroll
        for (int mask = 16; mask <= 32; mask <<= 1) {
            float o1 = __shfl_xor(a1, mask);
            float o2 = __shfl_xor(a2, mask);
            int   oi = __shfl_xor(ai, mask);
            bool  take = (o1 < a1) || (o1 == a1 && oi < ai);
            float n2   = take ? fminf(o2, a1) : fminf(a2, o1);
            a1 = take ? o1 : a1;
            ai = take ? oi : ai;
            a2 = n2;
        }
        if (l < 16) {
            int q = qw0 + qt * 16 + l15;
            ws_part[(size_t)q * SLICES + slice] =
                make_float4(a1, a2, __int_as_float(ai), 0.f);
        }
    }
#undef ISSUE_LOADS
#undef WRITE_LDS
#undef COMPUTE
}

// ---- K1b: merge slices, flag near-ties ----
__global__ __launch_bounds__(256) void k1b_merge(const float4* __restrict__ ws_part,
                                                 int* __restrict__ ws_idx,
                                                 int* __restrict__ ws_cnt,
                                                 int* __restrict__ ws_list) {
    int q = blockIdx.x * blockDim.x + threadIdx.x;
    float m1 = 1e30f, m2 = 1e30f;
    int   i1 = 0x7fffffff;
#pragma unroll
    for (int s = 0; s < SLICES; ++s) {
        float4 p = ws_part[(size_t)q * SLICES + s];
        float v1 = p.x, v2 = p.y;
        int   vi = __float_as_int(p.z);
        if (v1 < m1 || (v1 == m1 && vi < i1)) { m2 = fminf(m1, v2); m1 = v1; i1 = vi; }
        else                                  { m2 = fminf(m2, v1); }
    }
    ws_idx[q] = i1;
    if (m2 - m1 < TAU_V) {
        int r = atomicAdd(ws_cnt, 1);
        ws_list[r] = q;
    }
}

// ---- K2: fp64 exact rescan for near-tie queries ----
__global__ __launch_bounds__(256) void k2_rescue(const float* __restrict__ z,
                                                 const float* __restrict__ emb,
                                                 const int* __restrict__ ws_cnt,
                                                 const int* __restrict__ ws_list,
                                                 int* __restrict__ ws_idx) {
    __shared__ float  zrow[D];
    __shared__ double rv[256];
    __shared__ int    ri[256];
    const int cnt = *ws_cnt;
    for (int r = blockIdx.x; r < cnt; r += gridDim.x) {
        const int q = ws_list[r];
        __syncthreads();
        if (threadIdx.x < D) zrow[threadIdx.x] = z[(size_t)q * D + threadIdx.x];
        __syncthreads();
        double best = 1e300;
        int    bi   = 0x7fffffff;
        for (int c = threadIdx.x; c < K_CODES; c += 256) {
            const float4* er = (const float4*)(emb + (size_t)c * D);
            double acc = 0.0;
#pragma unroll
            for (int k = 0; k < 16; ++k) {
                float4 e  = er[k];
                double d0 = (double)zrow[4 * k + 0] - (double)e.x;
                double d1 = (double)zrow[4 * k + 1] - (double)e.y;
                double d2 = (double)zrow[4 * k + 2] - (double)e.z;
                double d3 = (double)zrow[4 * k + 3] - (double)e.w;
                acc += d0 * d0 + d1 * d1 + d2 * d2 + d3 * d3;
            }
            if (acc < best) { best = acc; bi = c; }
        }
        rv[threadIdx.x] = best;
        ri[threadIdx.x] = bi;
        __syncthreads();
        for (int s = 128; s > 0; s >>= 1) {
            if (threadIdx.x < s) {
                double ov = rv[threadIdx.x + s];
                int    oi = ri[threadIdx.x + s];
                if (ov < rv[threadIdx.x] || (ov == rv[threadIdx.x] && oi < ri[threadIdx.x])) {
                    rv[threadIdx.x] = ov;
                    ri[threadIdx.x] = oi;
                }
            }
            __syncthreads();
        }
        if (threadIdx.x == 0) ws_idx[q] = ri[0];
        __syncthreads();
    }
}

// ---- K3: gather z_q, emit idx as float, per-block loss partials ----
__global__ __launch_bounds__(256) void k3_gather(const float* __restrict__ emb,
                                                 const float* __restrict__ z,
                                                 const int* __restrict__ ws_idx,
                                                 float* __restrict__ out,
                                                 float* __restrict__ partial) {
    __shared__ float sb[256];
    int g = blockIdx.x * 256 + threadIdx.x;
    int q = g >> 6, d = g & 63;
    int id = ws_idx[q];
    float e = emb[(size_t)id * D + d];
    out[g] = e;
    if (d == 0) out[(size_t)M_QUERIES * D + q] = (float)id;
    float df = e - z[g];
    sb[threadIdx.x] = df * df;
    __syncthreads();
    for (int s = 128; s > 0; s >>= 1) {
        if (threadIdx.x < s) sb[threadIdx.x] += sb[threadIdx.x + s];
        __syncthreads();
    }
    if (threadIdx.x == 0) partial[blockIdx.x] = sb[0];
}

// ---- K4: final loss reduce ----
__global__ __launch_bounds__(256) void k4_loss(const float* __restrict__ partial,
                                               float* __restrict__ out) {
    __shared__ double sb[256];
    double s = 0.0;
    for (int i = threadIdx.x; i < (M_QUERIES * D) / 256; i += 256) s += (double)partial[i];
    sb[threadIdx.x] = s;
    __syncthreads();
    for (int st = 128; st > 0; st >>= 1) {
        if (threadIdx.x < st) sb[threadIdx.x] += sb[threadIdx.x + st];
        __syncthreads();
    }
    if (threadIdx.x == 0)
        out[(size_t)M_QUERIES * D + M_QUERIES] =
            (float)(1.25 * sb[0] / (double)((size_t)M_QUERIES * D));
}

extern "C" void kernel_launch(void* const* d_in, const int* in_sizes, int n_in,
                              void* d_out, int out_size, void* d_ws, size_t ws_size,
                              hipStream_t stream) {
    const float* z   = (const float*)d_in[0];
    const float* emb = (const float*)d_in[1];
    float* out = (float*)d_out;
    char*  ws  = (char*)d_ws;

    unsigned short* e_hi    = (unsigned short*)(ws);                    // 1 MB
    unsigned short* e_lo    = (unsigned short*)(ws + 1048576);          // 1 MB
    float*          halfee  = (float*)(ws + 2097152);                   // 32 KB
    float4*         ws_part = (float4*)(ws + 2129920);                  // 2 MB
    int*            ws_idx  = (int*)(ws + 2129920 + 2097152);           // 128 KB
    int*            ws_cnt  = (int*)(ws + 2129920 + 2097152 + 131072);  // 64 B
    int*            ws_list = (int*)(ws + 2129920 + 2097152 + 131136);  // 128 KB
    float*          partial = (float*)(ws + 2129920 + 2097152 + 262208);// 32 KB

    k0_split<<<K_CODES / 4, 256, 0, stream>>>(emb, e_hi, e_lo, halfee, ws_cnt);

    dim3 g1(M_QUERIES / QPB, SLICES);
    k1_mfma<<<g1, 256, 0, stream>>>(z, e_hi, e_lo, halfee, ws_part);

    k1b_merge<<<M_QUERIES / 256, 256, 0, stream>>>(ws_part, ws_idx, ws_cnt, ws_list);

    k2_rescue<<<256, 256, 0, stream>>>(z, emb, ws_cnt, ws_list, ws_idx);

    k3_gather<<<(M_QUERIES * D) / 256, 256, 0, stream>>>(emb, z, ws_idx, out, partial);

    k4_loss<<<1, 256, 0, stream>>>(partial, out);
}

// Round 6
// 245.737 us; speedup vs baseline: 1.0025x; 1.0025x over previous
//
#include <hip/hip_runtime.h>
#include <hip/hip_bf16.h>
#include <math.h>

#define D 64
#define K_CODES 8192
#define M_QUERIES 32768
#define SLICES 4
#define CODES_PER_SLICE (K_CODES / SLICES)  // 2048
#define CHUNK 64
#define NCHUNK (CODES_PER_SLICE / CHUNK)    // 32
#define QPB 128                              // queries per block = 4 waves * 32
#define TAU_V 4e-3f                          // gap threshold in v units (d2 gap = 2*v gap)

typedef __attribute__((ext_vector_type(8))) short bf16x8;
typedef __attribute__((ext_vector_type(4))) float f32x4;

__device__ __forceinline__ unsigned short f2bf(float x) {
    __hip_bfloat16 h = __float2bfloat16(x);
    return *reinterpret_cast<unsigned short*>(&h);
}
__device__ __forceinline__ float bf2f(unsigned short s) {
    __hip_bfloat16 h;
    *reinterpret_cast<unsigned short*>(&h) = s;
    return __bfloat162float(h);
}

// ---- K0: split emb into bf16 hi/lo, he' = 0.5*||e||^2 + 128, zero counter ----
__global__ __launch_bounds__(256) void k0_split(const float* __restrict__ emb,
                                                unsigned short* __restrict__ e_hi,
                                                unsigned short* __restrict__ e_lo,
                                                float* __restrict__ halfee,
                                                int* __restrict__ ws_cnt) {
    const int wid = threadIdx.x >> 6, l = threadIdx.x & 63;
    const int c = blockIdx.x * 4 + wid;
    if (c == 0 && l == 0) *ws_cnt = 0;
    float e = emb[(size_t)c * D + l];
    unsigned short h = f2bf(e);
    float r = e - bf2f(h);
    e_hi[(size_t)c * D + l] = h;
    e_lo[(size_t)c * D + l] = f2bf(r);
    float s = e * e;
#pragma unroll
    for (int m = 1; m < 64; m <<= 1) s += __shfl_xor(s, m);
    if (l == 0) halfee[c] = 0.5f * s + 128.0f;
}

// ---- K1: MFMA scoring v = he' - z.e (bf16 split), packed top-2 argmin ----
// __launch_bounds__(256, 1): MEASURED register-allocator behavior on this body:
//   (256,4) -> 64 VGPR, 283MB spill;  (256,2) -> 76, 45MB;
//   (256) bare -> 80, 48MB (default occupancy target is aggressive);
//   (256,1) -> 112, ZERO spill (round-2 evidence).
// 112 <= 128 still yields 4 waves/SIMD; LDS 33KB -> 4 blocks/CU -> 16 waves/CU.
__global__ __launch_bounds__(256, 1) void k1_mfma(const float* __restrict__ z,
                                                  const unsigned short* __restrict__ e_hi,
                                                  const unsigned short* __restrict__ e_lo,
                                                  const float* __restrict__ halfee,
                                                  float4* __restrict__ ws_part) {
    __shared__ unsigned short ldshi[2][CHUNK * 64];
    __shared__ unsigned short ldslo[2][CHUNK * 64];
    __shared__ float ldshe[2][CHUNK];

    const int tid = threadIdx.x;
    const int wid = tid >> 6;
    const int l   = tid & 63;
    const int l15 = l & 15, l16 = l >> 4;
    const int slice = blockIdx.y;
    const int cslice0 = slice * CODES_PER_SLICE;

    // this wave's 32 queries -> negated bf16 hi/lo B-fragments in regs
    const int qw0 = blockIdx.x * QPB + wid * 32;
    bf16x8 qh[2][2], ql[2][2];
#pragma unroll
    for (int qt = 0; qt < 2; ++qt)
#pragma unroll
        for (int kk = 0; kk < 2; ++kk) {
            const float* src = z + (size_t)(qw0 + qt * 16 + l15) * D + kk * 32 + l16 * 8;
            float4 f0 = *(const float4*)(src);
            float4 f1 = *(const float4*)(src + 4);
            float f[8] = {f0.x, f0.y, f0.z, f0.w, f1.x, f1.y, f1.z, f1.w};
            bf16x8 h, lo;
#pragma unroll
            for (int j = 0; j < 8; ++j) {
                float x = -f[j];
                unsigned short hh = f2bf(x);
                float r = x - bf2f(hh);
                h[j]  = (short)hh;
                lo[j] = (short)f2bf(r);
            }
            qh[qt][kk] = h;
            ql[qt][kk] = lo;
        }

    float g1[2] = {1e30f, 1e30f}, g2[2] = {1e30f, 1e30f};
    int   gi[2] = {0x7fffffff, 0x7fffffff};
    float4 rh[2], rl[2], rhe;

#define ISSUE_LOADS(c1)                                                          \
    {                                                                            \
        const char* bhi = (const char*)e_hi + (size_t)(cslice0 + (c1) * CHUNK) * 128; \
        const char* blo = (const char*)e_lo + (size_t)(cslice0 + (c1) * CHUNK) * 128; \
        _Pragma("unroll") for (int p = 0; p < 2; ++p) {                          \
            int idx = p * 256 + tid;                                             \
            rh[p] = *(const float4*)(bhi + idx * 16);                            \
            rl[p] = *(const float4*)(blo + idx * 16);                            \
        }                                                                        \
        if (tid < 16)                                                            \
            rhe = *(const float4*)((const char*)halfee +                         \
                                   (size_t)(cslice0 + (c1) * CHUNK) * 4 + tid * 16); \
    }

#define WRITE_LDS(buf)                                                           \
    {                                                                            \
        _Pragma("unroll") for (int p = 0; p < 2; ++p) {                          \
            int idx = p * 256 + tid;                                             \
            int r = idx >> 3, cc = idx & 7;                                      \
            int off = r * 128 + (cc ^ (r & 7)) * 16;                             \
            *(float4*)((char*)ldshi[buf] + off) = rh[p];                         \
            *(float4*)((char*)ldslo[buf] + off) = rl[p];                         \
        }                                                                        \
        if (tid < 16) *(float4*)((char*)ldshe[buf] + tid * 16) = rhe;            \
    }

#define COMPUTE(bufc, cbase)                                                     \
    {                                                                            \
        const char* bh  = (const char*)ldshi[bufc];                              \
        const char* bl  = (const char*)ldslo[bufc];                              \
        const float* bhe = ldshe[bufc];                                          \
        float m1p[2] = {1e30f, 1e30f}, m2p[2] = {1e30f, 1e30f};                  \
        _Pragma("unroll") for (int ct = 0; ct < 4; ++ct) {                       \
            int R0 = ct * 16 + l15;                                              \
            int rowb = R0 * 128;                                                 \
            int sw0 = ((l16)     ^ (R0 & 7)) * 16;                               \
            int sw1 = ((4 + l16) ^ (R0 & 7)) * 16;                               \
            bf16x8 ah0 = *(const bf16x8*)(bh + rowb + sw0);                      \
            bf16x8 ah1 = *(const bf16x8*)(bh + rowb + sw1);                      \
            bf16x8 al0 = *(const bf16x8*)(bl + rowb + sw0);                      \
            bf16x8 al1 = *(const bf16x8*)(bl + rowb + sw1);                      \
            f32x4 he = *(const f32x4*)(bhe + ct * 16 + l16 * 4);                 \
            _Pragma("unroll") for (int qt = 0; qt < 2; ++qt) {                   \
                f32x4 va;                                                        \
                va = __builtin_amdgcn_mfma_f32_16x16x32_bf16(ah0, qh[qt][0], he, 0, 0, 0); \
                va = __builtin_amdgcn_mfma_f32_16x16x32_bf16(ah1, qh[qt][1], va, 0, 0, 0); \
                va = __builtin_amdgcn_mfma_f32_16x16x32_bf16(ah0, ql[qt][0], va, 0, 0, 0); \
                va = __builtin_amdgcn_mfma_f32_16x16x32_bf16(ah1, ql[qt][1], va, 0, 0, 0); \
                va = __builtin_amdgcn_mfma_f32_16x16x32_bf16(al0, qh[qt][0], va, 0, 0, 0); \
                va = __builtin_amdgcn_mfma_f32_16x16x32_bf16(al1, qh[qt][1], va, 0, 0, 0); \
                _Pragma("unroll") for (int j = 0; j < 4; ++j) {                  \
                    int pos = ct * 4 + j;                                        \
                    float vp = __int_as_float((__float_as_int(va[j]) & 0xFFFFFFF0) | pos); \
                    m2p[qt] = __builtin_amdgcn_fmed3f(vp, m1p[qt], m2p[qt]);     \
                    m1p[qt] = fminf(m1p[qt], vp);                                \
                }                                                                \
            }                                                                    \
        }                                                                        \
        _Pragma("unroll") for (int qt = 0; qt < 2; ++qt) {                       \
            float v1 = m1p[qt];                                                  \
            int   p1 = __float_as_int(v1) & 15;                                  \
            int code = (cbase) + l16 * 4 + ((p1 >> 2) << 4) + (p1 & 3);          \
            bool lt = v1 < g1[qt];                                               \
            g2[qt] = fminf(lt ? g1[qt] : g2[qt], lt ? m2p[qt] : v1);             \
            g1[qt] = lt ? v1 : g1[qt];                                           \
            gi[qt] = lt ? code : gi[qt];                                         \
        }                                                                        \
    }

    ISSUE_LOADS(0);
    WRITE_LDS(0);
    __syncthreads();
    for (int c = 0; c < NCHUNK; ++c) {
        const int cur = c & 1;
        if (c + 1 < NCHUNK) ISSUE_LOADS(c + 1);
        COMPUTE(cur, cslice0 + c * CHUNK);
        __syncthreads();
        if (c + 1 < NCHUNK) WRITE_LDS(cur ^ 1);
        __syncthreads();
    }

    // lanes {l15, l15+16, l15+32, l15+48} share a query, hold disjoint codes
#pragma unroll
    for (int qt = 0; qt < 2; ++qt) {
        float a1 = g1[qt], a2 = g2[qt];
        int   ai = gi[qt];
#pragma unroll
        for (int mask = 16; mask <= 32; mask <<= 1) {
            float o1 = __shfl_xor(a1, mask);
            float o2 = __shfl_xor(a2, mask);
            int   oi = __shfl_xor(ai, mask);
            bool  take = (o1 < a1) || (o1 == a1 && oi < ai);
            float n2   = take ? fminf(o2, a1) : fminf(a2, o1);
            a1 = take ? o1 : a1;
            ai = take ? oi : ai;
            a2 = n2;
        }
        if (l < 16) {
            int q = qw0 + qt * 16 + l15;
            ws_part[(size_t)q * SLICES + slice] =
                make_float4(a1, a2, __int_as_float(ai), 0.f);
        }
    }
#undef ISSUE_LOADS
#undef WRITE_LDS
#undef COMPUTE
}

// ---- K1b: merge slices, flag near-ties ----
__global__ __launch_bounds__(256) void k1b_merge(const float4* __restrict__ ws_part,
                                                 int* __restrict__ ws_idx,
                                                 int* __restrict__ ws_cnt,
                                                 int* __restrict__ ws_list) {
    int q = blockIdx.x * blockDim.x + threadIdx.x;
    float m1 = 1e30f, m2 = 1e30f;
    int   i1 = 0x7fffffff;
#pragma unroll
    for (int s = 0; s < SLICES; ++s) {
        float4 p = ws_part[(size_t)q * SLICES + s];
        float v1 = p.x, v2 = p.y;
        int   vi = __float_as_int(p.z);
        if (v1 < m1 || (v1 == m1 && vi < i1)) { m2 = fminf(m1, v2); m1 = v1; i1 = vi; }
        else                                  { m2 = fminf(m2, v1); }
    }
    ws_idx[q] = i1;
    if (m2 - m1 < TAU_V) {
        int r = atomicAdd(ws_cnt, 1);
        ws_list[r] = q;
    }
}

// ---- K2: fp64 exact rescan for near-tie queries ----
__global__ __launch_bounds__(256) void k2_rescue(const float* __restrict__ z,
                                                 const float* __restrict__ emb,
                                                 const int* __restrict__ ws_cnt,
                                                 const int* __restrict__ ws_list,
                                                 int* __restrict__ ws_idx) {
    __shared__ float  zrow[D];
    __shared__ double rv[256];
    __shared__ int    ri[256];
    const int cnt = *ws_cnt;
    for (int r = blockIdx.x; r < cnt; r += gridDim.x) {
        const int q = ws_list[r];
        __syncthreads();
        if (threadIdx.x < D) zrow[threadIdx.x] = z[(size_t)q * D + threadIdx.x];
        __syncthreads();
        double best = 1e300;
        int    bi   = 0x7fffffff;
        for (int c = threadIdx.x; c < K_CODES; c += 256) {
            const float4* er = (const float4*)(emb + (size_t)c * D);
            double acc = 0.0;
#pragma unroll
            for (int k = 0; k < 16; ++k) {
                float4 e  = er[k];
                double d0 = (double)zrow[4 * k + 0] - (double)e.x;
                double d1 = (double)zrow[4 * k + 1] - (double)e.y;
                double d2 = (double)zrow[4 * k + 2] - (double)e.z;
                double d3 = (double)zrow[4 * k + 3] - (double)e.w;
                acc += d0 * d0 + d1 * d1 + d2 * d2 + d3 * d3;
            }
            if (acc < best) { best = acc; bi = c; }
        }
        rv[threadIdx.x] = best;
        ri[threadIdx.x] = bi;
        __syncthreads();
        for (int s = 128; s > 0; s >>= 1) {
            if (threadIdx.x < s) {
                double ov = rv[threadIdx.x + s];
                int    oi = ri[threadIdx.x + s];
                if (ov < rv[threadIdx.x] || (ov == rv[threadIdx.x] && oi < ri[threadIdx.x])) {
                    rv[threadIdx.x] = ov;
                    ri[threadIdx.x] = oi;
                }
            }
            __syncthreads();
        }
        if (threadIdx.x == 0) ws_idx[q] = ri[0];
        __syncthreads();
    }
}

// ---- K3: gather z_q, emit idx as float, per-block loss partials ----
__global__ __launch_bounds__(256) void k3_gather(const float* __restrict__ emb,
                                                 const float* __restrict__ z,
                                                 const int* __restrict__ ws_idx,
                                                 float* __restrict__ out,
                                                 float* __restrict__ partial) {
    __shared__ float sb[256];
    int g = blockIdx.x * 256 + threadIdx.x;
    int q = g >> 6, d = g & 63;
    int id = ws_idx[q];
    float e = emb[(size_t)id * D + d];
    out[g] = e;
    if (d == 0) out[(size_t)M_QUERIES * D + q] = (float)id;
    float df = e - z[g];
    sb[threadIdx.x] = df * df;
    __syncthreads();
    for (int s = 128; s > 0; s >>= 1) {
        if (threadIdx.x < s) sb[threadIdx.x] += sb[threadIdx.x + s];
        __syncthreads();
    }
    if (threadIdx.x == 0) partial[blockIdx.x] = sb[0];
}

// ---- K4: final loss reduce ----
__global__ __launch_bounds__(256) void k4_loss(const float* __restrict__ partial,
                                               float* __restrict__ out) {
    __shared__ double sb[256];
    double s = 0.0;
    for (int i = threadIdx.x; i < (M_QUERIES * D) / 256; i += 256) s += (double)partial[i];
    sb[threadIdx.x] = s;
    __syncthreads();
    for (int st = 128; st > 0; st >>= 1) {
        if (threadIdx.x < st) sb[threadIdx.x] += sb[threadIdx.x + st];
        __syncthreads();
    }
    if (threadIdx.x == 0)
        out[(size_t)M_QUERIES * D + M_QUERIES] =
            (float)(1.25 * sb[0] / (double)((size_t)M_QUERIES * D));
}

extern "C" void kernel_launch(void* const* d_in, const int* in_sizes, int n_in,
                              void* d_out, int out_size, void* d_ws, size_t ws_size,
                              hipStream_t stream) {
    const float* z   = (const float*)d_in[0];
    const float* emb = (const float*)d_in[1];
    float* out = (float*)d_out;
    char*  ws  = (char*)d_ws;

    unsigned short* e_hi    = (unsigned short*)(ws);                    // 1 MB
    unsigned short* e_lo    = (unsigned short*)(ws + 1048576);          // 1 MB
    float*          halfee  = (float*)(ws + 2097152);                   // 32 KB
    float4*         ws_part = (float4*)(ws + 2129920);                  // 2 MB
    int*            ws_idx  = (int*)(ws + 2129920 + 2097152);           // 128 KB
    int*            ws_cnt  = (int*)(ws + 2129920 + 2097152 + 131072);  // 64 B
    int*            ws_list = (int*)(ws + 2129920 + 2097152 + 131136);  // 128 KB
    float*          partial = (float*)(ws + 2129920 + 2097152 + 262208);// 32 KB

    k0_split<<<K_CODES / 4, 256, 0, stream>>>(emb, e_hi, e_lo, halfee, ws_cnt);

    dim3 g1(M_QUERIES / QPB, SLICES);
    k1_mfma<<<g1, 256, 0, stream>>>(z, e_hi, e_lo, halfee, ws_part);

    k1b_merge<<<M_QUERIES / 256, 256, 0, stream>>>(ws_part, ws_idx, ws_cnt, ws_list);

    k2_rescue<<<256, 256, 0, stream>>>(z, emb, ws_cnt, ws_list, ws_idx);

    k3_gather<<<(M_QUERIES * D) / 256, 256, 0, stream>>>(emb, z, ws_idx, out, partial);

    k4_loss<<<1, 256, 0, stream>>>(partial, out);
}